// Round 2
// baseline (394.664 us; speedup 1.0000x reference)
//
#include <hip/hip_runtime.h>
#include <math.h>

#define KNN 16
#define DIM 128
#define BQ 256
#define NDB 100000
#define NC 512                   // db rows per block
#define NBLK 196                 // ceil(100000/512)
#define CAND_PER_Q (NBLK * KNN)  // 3136
#define RPP 32                   // rows per phase
#define NPH (NC / RPP)           // 16
#define STRQ 264                 // padded query stride in dist LDS
#define TAU_INV 10.0f
#define EPSC 1e-8f
#define FBIG 3.402823e38f

typedef float f32x4 __attribute__((ext_vector_type(4)));
typedef unsigned int uint4v __attribute__((ext_vector_type(4)));
typedef __bf16 bf16x8 __attribute__((ext_vector_type(8)));

union U8 { uint4v u; bf16x8 b; };

__device__ __forceinline__ unsigned pack_bf(unsigned lo, unsigned hi) {
    // truncate two f32 (bit patterns) to bf16 pair: low short = lo's bf16
    return (lo >> 16) | (hi & 0xFFFF0000u);
}

// ---------------- Kernel A: Tq = q_batch @ W (f32 + bf16 copies) ----------------
__global__ void k_tq(const float* __restrict__ qb, const float* __restrict__ W,
                     float* __restrict__ Tq, unsigned short* __restrict__ Tqb) {
    int b = blockIdx.x, c = threadIdx.x;   // 128 threads
    __shared__ float qs[DIM];
    qs[c] = qb[b * DIM + c];
    __syncthreads();
    float acc = 0.f;
#pragma unroll 8
    for (int k = 0; k < DIM; ++k) acc = fmaf(qs[k], W[k * DIM + c], acc);
    Tq[b * DIM + c] = acc;
    unsigned bits = __float_as_uint(acc);
    unsigned r = (bits + 0x7FFFu + ((bits >> 16) & 1u)) >> 16;   // RNE to bf16
    Tqb[b * DIM + c] = (unsigned short)r;
}

// ---------------- Kernel B: xsq[j] = ||X[j]||^2 ----------------
__global__ void k_xsq(const float* __restrict__ X, float* __restrict__ xsq) {
    int row = blockIdx.x * 4 + (threadIdx.x >> 6);
    int lane = threadIdx.x & 63;
    if (row >= NDB) return;
    const float2* xr = reinterpret_cast<const float2*>(X + (size_t)row * DIM);
    float2 v = xr[lane];
    float s = fmaf(v.x, v.x, v.y * v.y);
#pragma unroll
    for (int m = 32; m >= 1; m >>= 1) s += __shfl_xor(s, m, 64);
    if (lane == 0) xsq[row] = s;
}

// ---------------- Kernel C: MFMA distances + per-(query,chunk) top-16 ----------------
__launch_bounds__(256, 2)
__global__ void k_dist(const unsigned short* __restrict__ Tqb,
                       const float* __restrict__ X, const float* __restrict__ xsq,
                       float* __restrict__ cand_d, int* __restrict__ cand_i) {
    __shared__ float dist_lds[RPP * STRQ];   // [n within phase][query], padded
    const int t = threadIdx.x;
    const int w = t >> 6;          // wave 0..3 -> queries [64w, 64w+64)
    const int lane = t & 63;
    const int la = lane >> 4;      // 0..3
    const int lb = lane & 15;      // 0..15
    const int j0 = blockIdx.x * NC;

    // resident A fragments: Tq_bf16 for this wave's 64 queries, all K=128
    // A layout (16x16x32): row = lane&15, k = (lane>>4)*8 + e  (8 contiguous bf16)
    bf16x8 afr[4][4];
#pragma unroll
    for (int mt = 0; mt < 4; ++mt) {
#pragma unroll
        for (int ks = 0; ks < 4; ++ks) {
            const uint4v* p = reinterpret_cast<const uint4v*>(
                Tqb + (size_t)(w * 64 + mt * 16 + lb) * DIM + ks * 32 + la * 8);
            U8 u; u.u = *p;
            afr[mt][ks] = u.b;
        }
    }

    float td[KNN]; int ti[KNN];
#pragma unroll
    for (int i = 0; i < KNN; ++i) { td[i] = FBIG; ti[i] = -1; }

    for (int ph = 0; ph < NPH; ++ph) {
        const int r0 = ph * RPP;
        // compute phase: each wave computes its 64 queries x 32 rows
#pragma unroll
        for (int nt = 0; nt < 2; ++nt) {
            int j = j0 + r0 + nt * 16 + lb;
            int jc = (j < NDB) ? j : (NDB - 1);
            const unsigned* xr = reinterpret_cast<const unsigned*>(X + (size_t)jc * DIM);
            // B layout: col = lane&15 (db row), k = (lane>>4)*8 + e
            bf16x8 bfr[4];
#pragma unroll
            for (int ks = 0; ks < 4; ++ks) {
                uint4v va = *reinterpret_cast<const uint4v*>(xr + ks * 32 + la * 8);
                uint4v vb = *reinterpret_cast<const uint4v*>(xr + ks * 32 + la * 8 + 4);
                uint4v pk = { pack_bf(va[0], va[1]), pack_bf(va[2], va[3]),
                              pack_bf(vb[0], vb[1]), pack_bf(vb[2], vb[3]) };
                U8 u; u.u = pk;
                bfr[ks] = u.b;
            }
            float xs = xsq[jc];
            bool oob = (j >= NDB);
            const int n = nt * 16 + lb;
#pragma unroll
            for (int mt = 0; mt < 4; ++mt) {
                f32x4 acc = {0.f, 0.f, 0.f, 0.f};
#pragma unroll
                for (int ks = 0; ks < 4; ++ks)
                    acc = __builtin_amdgcn_mfma_f32_16x16x32_bf16(afr[mt][ks], bfr[ks], acc, 0, 0, 0);
                f32x4 val;
#pragma unroll
                for (int r = 0; r < 4; ++r) val[r] = oob ? FBIG : (xs - 2.0f * acc[r]);
                // C/D layout: col = lane&15 (db row n), row = (lane>>4)*4 + r (query)
                *reinterpret_cast<f32x4*>(&dist_lds[n * STRQ + w * 64 + mt * 16 + la * 4]) = val;
            }
        }
        __syncthreads();
        // select phase: thread t owns query t, scans 32 rows
#pragma unroll 8
        for (int n = 0; n < RPP; ++n) {
            float dv = dist_lds[n * STRQ + t];
            if (dv < td[KNN - 1]) {
                float d = dv; int id = j0 + r0 + n;
#pragma unroll
                for (int i = 0; i < KNN; ++i) {
                    bool lt = d < td[i];
                    float nd = lt ? d : td[i];  int nid = lt ? id : ti[i];
                    float od = lt ? td[i] : d;  int oid = lt ? ti[i] : id;
                    td[i] = nd; ti[i] = nid; d = od; id = oid;
                }
            }
        }
        __syncthreads();
    }

    size_t base = ((size_t)t * NBLK + blockIdx.x) * KNN;
#pragma unroll
    for (int i = 0; i < KNN; ++i) { cand_d[base + i] = td[i]; cand_i[base + i] = ti[i]; }
}

// ---------------- Kernel D: per-query merge + exact l2 + softmax + union KL ----------------
__global__ void k_final(const float* __restrict__ Tq, const float* __restrict__ X,
                        const float* __restrict__ cand_d, const int* __restrict__ cand_i,
                        const int* __restrict__ q_indices,
                        const int* __restrict__ pre_indices,
                        const float* __restrict__ pre_weights,
                        float* __restrict__ kl_out) {
    const int q = blockIdx.x, t = threadIdx.x;
    __shared__ float sdA[256 * KNN]; __shared__ int siA[256 * KNN];
    __shared__ float sdB[128 * KNN]; __shared__ int siB[128 * KNN];
    __shared__ int post_idx[KNN];
    __shared__ float l2s[KNN];
    __shared__ float post_w[KNN];
    __shared__ int u_idx[2 * KNN]; __shared__ float u_p[2 * KNN]; __shared__ float u_q[2 * KNN];

    float td[KNN]; int ti[KNN];
#pragma unroll
    for (int i = 0; i < KNN; ++i) { td[i] = FBIG; ti[i] = -1; }
    const float* cd = cand_d + (size_t)q * CAND_PER_Q;
    const int* ci = cand_i + (size_t)q * CAND_PER_Q;
    for (int e = t; e < CAND_PER_Q; e += 256) {
        float dist = cd[e];
        if (dist < td[KNN - 1]) {
            float d = dist; int id = ci[e];
#pragma unroll
            for (int i = 0; i < KNN; ++i) {
                bool lt = d < td[i];
                float nd = lt ? d : td[i];  int nid = lt ? id : ti[i];
                float od = lt ? td[i] : d;  int oid = lt ? ti[i] : id;
                td[i] = nd; ti[i] = nid; d = od; id = oid;
            }
        }
    }
#pragma unroll
    for (int i = 0; i < KNN; ++i) { sdA[t * KNN + i] = td[i]; siA[t * KNN + i] = ti[i]; }

    float* sd = sdA; int* si = siA; float* dd = sdB; int* di = siB;
    int cnt = 256;
    while (cnt > 1) {
        __syncthreads();
        int h = cnt >> 1;
        if (t < h) {
            int i = 0, jj = 0;
#pragma unroll
            for (int o = 0; o < KNN; ++o) {
                float a = (i < KNN) ? sd[t * KNN + i] : FBIG;
                float b2 = (jj < KNN) ? sd[(t + h) * KNN + jj] : FBIG;
                if (a <= b2) { dd[t * KNN + o] = a; di[t * KNN + o] = si[t * KNN + i]; ++i; }
                else         { dd[t * KNN + o] = b2; di[t * KNN + o] = si[(t + h) * KNN + jj]; ++jj; }
            }
        }
        float* tf = sd; sd = dd; dd = tf;
        int* ts = si; si = di; di = ts;
        cnt = h;
    }
    __syncthreads();
    if (t < KNN) post_idx[t] = si[t];
    __syncthreads();

    {
        int n = t >> 4, l = t & 15;
        int idx = post_idx[n];
        const float* tr = Tq + q * DIM + l * 8;
        const float* xr = X + (size_t)idx * DIM + l * 8;
        float s = 0.f;
#pragma unroll
        for (int kk = 0; kk < 8; ++kk) { float df = tr[kk] - xr[kk]; s = fmaf(df, df, s); }
#pragma unroll
        for (int m = 1; m < 16; m <<= 1) s += __shfl_xor(s, m, 64);
        if (l == 0) l2s[n] = s;
    }
    __syncthreads();

    if (t == 0) {
        float mx = -FBIG;
        for (int i = 0; i < KNN; ++i) { float v = -l2s[i] * TAU_INV; post_w[i] = v; if (v > mx) mx = v; }
        float sum = 0.f;
        for (int i = 0; i < KNN; ++i) { float e = expf(post_w[i] - mx); post_w[i] = e; sum += e; }
        float inv = 1.f / sum;
        for (int i = 0; i < KNN; ++i) post_w[i] *= inv;

        int qi = q_indices[q];
        int cnt2 = KNN;
        for (int i = 0; i < KNN; ++i) { u_idx[i] = post_idx[i]; u_q[i] = post_w[i]; u_p[i] = 0.f; }
        for (int m = 0; m < KNN; ++m) {
            int pi = pre_indices[qi * KNN + m];
            float pwm = pre_weights[qi * KNN + m];
            int f = -1;
            for (int s2 = 0; s2 < cnt2; ++s2) if (u_idx[s2] == pi) { f = s2; break; }
            if (f >= 0) u_p[f] = pwm;
            else { u_idx[cnt2] = pi; u_p[cnt2] = pwm; u_q[cnt2] = 0.f; ++cnt2; }
        }
        float Zp = 0.f, Zq = 0.f;
        for (int s2 = 0; s2 < cnt2; ++s2) { Zp += fmaxf(u_p[s2], EPSC); Zq += fmaxf(u_q[s2], EPSC); }
        float kl = 0.f;
        float izp = 1.f / Zp, izq = 1.f / Zq;
        for (int s2 = 0; s2 < cnt2; ++s2) {
            float pp = fmaxf(u_p[s2], EPSC) * izp;
            float qv = fmaxf(u_q[s2], EPSC) * izq;
            kl += pp * (logf(pp) - logf(qv));
        }
        kl_out[q] = kl;
    }
}

// ---------------- Kernel E: final reduction + outputs ----------------
__global__ void k_out(const float* __restrict__ kl, const float* __restrict__ W,
                      float* __restrict__ out) {
    int t = threadIdx.x;
    float s_kl = (t < BQ) ? kl[t] : 0.f;
    float s_w = 0.f;
    for (int i = t; i < DIM * DIM; i += 256) { float w = W[i]; s_w = fmaf(w, w, s_w); }
#pragma unroll
    for (int m = 32; m >= 1; m >>= 1) {
        s_kl += __shfl_xor(s_kl, m, 64);
        s_w += __shfl_xor(s_w, m, 64);
    }
    __shared__ float rk[4], rw[4];
    if ((t & 63) == 0) { rk[t >> 6] = s_kl; rw[t >> 6] = s_w; }
    __syncthreads();
    if (t == 0) {
        float kls = rk[0] + rk[1] + rk[2] + rk[3];
        float wss = rw[0] + rw[1] + rw[2] + rw[3];
        float knn = kls * (1.0f / BQ);
        float reg = 0.5f * wss;
        out[0] = 1.0f * knn + 1e-4f * reg;
        out[1] = 0.f;
        out[2] = knn;
    }
}

extern "C" void kernel_launch(void* const* d_in, const int* in_sizes, int n_in,
                              void* d_out, int out_size, void* d_ws, size_t ws_size,
                              hipStream_t stream) {
    const float* q_batch     = (const float*)d_in[0];
    const int*   q_indices   = (const int*)d_in[1];
    const float* X           = (const float*)d_in[2];
    const float* W           = (const float*)d_in[3];
    const int*   pre_indices = (const int*)d_in[4];
    const float* pre_weights = (const float*)d_in[5];

    float* ws = (float*)d_ws;
    float* Tq = ws;                                        // 32768 f32
    unsigned short* Tqb = (unsigned short*)(ws + 32768);   // 32768 bf16
    float* xsq = ws + 32768 + 16384;                       // 100000
    float* klv = xsq + NDB;                                // 256
    float* cand_d = klv + BQ;                              // 256*196*16
    int*   cand_i = (int*)(cand_d + (size_t)BQ * NBLK * KNN);

    k_tq<<<dim3(BQ), dim3(DIM), 0, stream>>>(q_batch, W, Tq, Tqb);
    k_xsq<<<dim3((NDB + 3) / 4), dim3(256), 0, stream>>>(X, xsq);
    k_dist<<<dim3(NBLK), dim3(256), 0, stream>>>(Tqb, X, xsq, cand_d, cand_i);
    k_final<<<dim3(BQ), dim3(256), 0, stream>>>(Tq, X, cand_d, cand_i,
                                                q_indices, pre_indices, pre_weights, klv);
    k_out<<<dim3(1), dim3(256), 0, stream>>>(klv, W, (float*)d_out);
}

// Round 3
// 308.584 us; speedup vs baseline: 1.2790x; 1.2790x over previous
//
#include <hip/hip_runtime.h>
#include <math.h>

#define KNN 16
#define DIM 128
#define BQ 256
#define NDB 100000
#define NC 256                   // db rows per block
#define NBLK 391                 // ceil(100000/256)
#define CAND_PER_Q (NBLK * KNN)  // 6256
#define RPP 32                   // rows per phase
#define NPH (NC / RPP)           // 8
#define STRQ 264                 // padded query stride in dist LDS
#define TAU_INV 10.0f
#define EPSC 1e-8f
#define FBIG 3.402823e38f

typedef float f32x4 __attribute__((ext_vector_type(4)));
typedef __bf16 bf16x8 __attribute__((ext_vector_type(8)));
typedef unsigned short ushort;
typedef ushort ushort8 __attribute__((ext_vector_type(8)));

__device__ __forceinline__ ushort f32_to_bf16_rne(float v) {
    unsigned bits = __float_as_uint(v);
    return (ushort)((bits + 0x7FFFu + ((bits >> 16) & 1u)) >> 16);
}

// ---------------- Kernel A: Tq = q_batch @ W (f32 + bf16 copies) ----------------
__global__ void k_tq(const float* __restrict__ qb, const float* __restrict__ W,
                     float* __restrict__ Tq, ushort* __restrict__ Tqb) {
    int b = blockIdx.x, c = threadIdx.x;   // 128 threads
    __shared__ float qs[DIM];
    qs[c] = qb[b * DIM + c];
    __syncthreads();
    float acc = 0.f;
#pragma unroll 8
    for (int k = 0; k < DIM; ++k) acc = fmaf(qs[k], W[k * DIM + c], acc);
    Tq[b * DIM + c] = acc;
    Tqb[b * DIM + c] = f32_to_bf16_rne(acc);
}

// ---------------- Kernel B: X -> bf16 (row-swizzled) + xsq ----------------
// Xbf row j stores 16B-chunk c at position (c ^ (j&7)) within the row.
__global__ void k_xbf(const float* __restrict__ X, ushort* __restrict__ Xbf,
                      float* __restrict__ xsq) {
    const int g = blockIdx.x * 256 + threadIdx.x;   // 1.6M = 100000 rows * 16 chunks
    const int j = g >> 4, c = g & 15;
    const float4* src = reinterpret_cast<const float4*>(X + (size_t)j * DIM + c * 8);
    float4 v0 = src[0], v1 = src[1];
    float s = v0.x * v0.x + v0.y * v0.y + v0.z * v0.z + v0.w * v0.w
            + v1.x * v1.x + v1.y * v1.y + v1.z * v1.z + v1.w * v1.w;
    ushort8 o;
    o[0] = f32_to_bf16_rne(v0.x); o[1] = f32_to_bf16_rne(v0.y);
    o[2] = f32_to_bf16_rne(v0.z); o[3] = f32_to_bf16_rne(v0.w);
    o[4] = f32_to_bf16_rne(v1.x); o[5] = f32_to_bf16_rne(v1.y);
    o[6] = f32_to_bf16_rne(v1.z); o[7] = f32_to_bf16_rne(v1.w);
    *reinterpret_cast<ushort8*>(Xbf + (size_t)j * DIM + ((c ^ (j & 7)) << 3)) = o;
#pragma unroll
    for (int m = 1; m < 16; m <<= 1) s += __shfl_xor(s, m, 64);
    if (c == 0) xsq[j] = s;
}

// ---------------- Kernel C: MFMA distances + per-(query,chunk) top-16 ----------------
// 391 blocks x 256 threads. LDS-staged B (double-buffered, reg-prefetch),
// raw barriers so prefetch loads stay in flight.
__global__ __launch_bounds__(256, 2)
void k_dist(const ushort* __restrict__ Tqb, const ushort* __restrict__ Xbf,
            const float* __restrict__ xsq,
            float* __restrict__ cand_d, int* __restrict__ cand_i) {
    __shared__ ushort xb[2][RPP * DIM];      // 2 x 8KB bf16 tiles (rows swizzled)
    __shared__ float dist_lds[RPP * STRQ];   // 33.8KB [row][query]
    const int t = threadIdx.x;
    const int w = t >> 6;          // wave -> queries [64w, 64w+64)
    const int lane = t & 63;
    const int la = lane >> 4;      // 0..3
    const int lb = lane & 15;      // 0..15
    const int j0 = blockIdx.x * NC;

    // A fragments: 64 queries x K=128 (row = lane&15, k = (lane>>4)*8 + ks*32)
    bf16x8 afr[4][4];
#pragma unroll
    for (int mt = 0; mt < 4; ++mt)
#pragma unroll
        for (int ks = 0; ks < 4; ++ks)
            afr[mt][ks] = *reinterpret_cast<const bf16x8*>(
                Tqb + (size_t)(w * 64 + mt * 16 + lb) * DIM + ks * 32 + la * 8);

    float td[KNN]; int ti[KNN];
#pragma unroll
    for (int i = 0; i < KNN; ++i) { td[i] = FBIG; ti[i] = -1; }

    // prolog: stage phase 0 (each thread copies 32B; swizzled layout copied verbatim)
    {
        const ushort* src = Xbf + (size_t)j0 * DIM + t * 16;
        bf16x8 a0 = *reinterpret_cast<const bf16x8*>(src);
        bf16x8 a1 = *reinterpret_cast<const bf16x8*>(src + 8);
        *reinterpret_cast<bf16x8*>(&xb[0][t * 16]) = a0;
        *reinterpret_cast<bf16x8*>(&xb[0][t * 16 + 8]) = a1;
    }

    for (int ph = 0; ph < NPH; ++ph) {
        const int cur = ph & 1, nxt = cur ^ 1;
        const int rbase = j0 + ph * RPP;
        // prefetch next tile into regs (fire-and-forget; compiler handles vmcnt)
        bf16x8 nv0, nv1;
        if (ph + 1 < NPH) {
            const ushort* src = Xbf + (size_t)(rbase + RPP) * DIM + t * 16;
            nv0 = *reinterpret_cast<const bf16x8*>(src);
            nv1 = *reinterpret_cast<const bf16x8*>(src + 8);
        }
        int jA = rbase + lb, jB = rbase + 16 + lb;
        float xsA = xsq[jA < NDB ? jA : NDB - 1];
        float xsB = xsq[jB < NDB ? jB : NDB - 1];

        asm volatile("s_waitcnt lgkmcnt(0)" ::: "memory");
        __builtin_amdgcn_s_barrier();            // xb[cur] fully written

#pragma unroll
        for (int nt = 0; nt < 2; ++nt) {
            const int row = nt * 16 + lb;
            bf16x8 bfr[4];
#pragma unroll
            for (int ks = 0; ks < 4; ++ks)
                bfr[ks] = *reinterpret_cast<const bf16x8*>(
                    &xb[cur][row * DIM + (((ks * 4 + la) ^ (lb & 7)) << 3)]);
            const float xs = nt ? xsB : xsA;
            const int j = rbase + row;
            const bool oob = (j >= NDB);
#pragma unroll
            for (int mt = 0; mt < 4; ++mt) {
                f32x4 acc = {0.f, 0.f, 0.f, 0.f};
#pragma unroll
                for (int ks = 0; ks < 4; ++ks)
                    acc = __builtin_amdgcn_mfma_f32_16x16x32_bf16(afr[mt][ks], bfr[ks], acc, 0, 0, 0);
                f32x4 val;
#pragma unroll
                for (int r = 0; r < 4; ++r) val[r] = oob ? FBIG : (xs - 2.f * acc[r]);
                // C/D: col = lane&15 (db row), row = (lane>>4)*4 + r (query)
                *reinterpret_cast<f32x4*>(&dist_lds[row * STRQ + w * 64 + mt * 16 + la * 4]) = val;
            }
        }
        asm volatile("s_waitcnt lgkmcnt(0)" ::: "memory");
        __builtin_amdgcn_s_barrier();            // dist_lds fully written

        // select: thread t owns query t
#pragma unroll 8
        for (int n = 0; n < RPP; ++n) {
            float dv = dist_lds[n * STRQ + t];
            if (dv < td[KNN - 1]) {
                float d = dv; int id = rbase + n;
#pragma unroll
                for (int i = 0; i < KNN; ++i) {
                    bool lt = d < td[i];
                    float nd = lt ? d : td[i];  int nid = lt ? id : ti[i];
                    float od = lt ? td[i] : d;  int oid = lt ? ti[i] : id;
                    td[i] = nd; ti[i] = nid; d = od; id = oid;
                }
            }
        }
        __builtin_amdgcn_s_barrier();            // dist_lds free for next phase

        if (ph + 1 < NPH) {                      // write-late: stage next tile
            *reinterpret_cast<bf16x8*>(&xb[nxt][t * 16]) = nv0;
            *reinterpret_cast<bf16x8*>(&xb[nxt][t * 16 + 8]) = nv1;
        }
    }

    // coalesced candidate store: [blk][q][16]
    size_t base = ((size_t)blockIdx.x * BQ + t) * KNN;
#pragma unroll
    for (int i = 0; i < KNN; ++i) { cand_d[base + i] = td[i]; cand_i[base + i] = ti[i]; }
}

// ---------------- Kernel D: per-query merge + exact l2 + softmax + union KL ----------------
__global__ void k_final(const float* __restrict__ Tq, const float* __restrict__ X,
                        const float* __restrict__ cand_d, const int* __restrict__ cand_i,
                        const int* __restrict__ q_indices,
                        const int* __restrict__ pre_indices,
                        const float* __restrict__ pre_weights,
                        float* __restrict__ kl_out) {
    const int q = blockIdx.x, t = threadIdx.x;
    __shared__ float sdA[256 * KNN]; __shared__ int siA[256 * KNN];
    __shared__ float sdB[128 * KNN]; __shared__ int siB[128 * KNN];
    __shared__ int post_idx[KNN];
    __shared__ float l2s[KNN];
    __shared__ float post_w[KNN];
    __shared__ int u_idx[2 * KNN]; __shared__ float u_p[2 * KNN]; __shared__ float u_q[2 * KNN];

    float td[KNN]; int ti[KNN];
#pragma unroll
    for (int i = 0; i < KNN; ++i) { td[i] = FBIG; ti[i] = -1; }
    for (int e = t; e < CAND_PER_Q; e += 256) {
        int blk = e >> 4, i2 = e & 15;
        size_t a = ((size_t)blk * BQ + q) * KNN + i2;
        float dist = cand_d[a];
        if (dist < td[KNN - 1]) {
            float d = dist; int id = cand_i[a];
#pragma unroll
            for (int i = 0; i < KNN; ++i) {
                bool lt = d < td[i];
                float nd = lt ? d : td[i];  int nid = lt ? id : ti[i];
                float od = lt ? td[i] : d;  int oid = lt ? ti[i] : id;
                td[i] = nd; ti[i] = nid; d = od; id = oid;
            }
        }
    }
#pragma unroll
    for (int i = 0; i < KNN; ++i) { sdA[t * KNN + i] = td[i]; siA[t * KNN + i] = ti[i]; }

    float* sd = sdA; int* si = siA; float* dd = sdB; int* di = siB;
    int cnt = 256;
    while (cnt > 1) {
        __syncthreads();
        int h = cnt >> 1;
        if (t < h) {
            int i = 0, jj = 0;
#pragma unroll
            for (int o = 0; o < KNN; ++o) {
                float a = (i < KNN) ? sd[t * KNN + i] : FBIG;
                float b2 = (jj < KNN) ? sd[(t + h) * KNN + jj] : FBIG;
                if (a <= b2) { dd[t * KNN + o] = a; di[t * KNN + o] = si[t * KNN + i]; ++i; }
                else         { dd[t * KNN + o] = b2; di[t * KNN + o] = si[(t + h) * KNN + jj]; ++jj; }
            }
        }
        float* tf = sd; sd = dd; dd = tf;
        int* ts = si; si = di; di = ts;
        cnt = h;
    }
    __syncthreads();
    if (t < KNN) post_idx[t] = si[t];
    __syncthreads();

    {   // exact f32 l2 for the selected 16 (16 threads x 8 dims each)
        int n = t >> 4, l = t & 15;
        int idx = post_idx[n];
        const float* tr = Tq + q * DIM + l * 8;
        const float* xr = X + (size_t)idx * DIM + l * 8;
        float s = 0.f;
#pragma unroll
        for (int kk = 0; kk < 8; ++kk) { float df = tr[kk] - xr[kk]; s = fmaf(df, df, s); }
#pragma unroll
        for (int m = 1; m < 16; m <<= 1) s += __shfl_xor(s, m, 64);
        if (l == 0) l2s[n] = s;
    }
    __syncthreads();

    if (t == 0) {
        float mx = -FBIG;
        for (int i = 0; i < KNN; ++i) { float v = -l2s[i] * TAU_INV; post_w[i] = v; if (v > mx) mx = v; }
        float sum = 0.f;
        for (int i = 0; i < KNN; ++i) { float e = expf(post_w[i] - mx); post_w[i] = e; sum += e; }
        float inv = 1.f / sum;
        for (int i = 0; i < KNN; ++i) post_w[i] *= inv;

        int qi = q_indices[q];
        int cnt2 = KNN;
        for (int i = 0; i < KNN; ++i) { u_idx[i] = post_idx[i]; u_q[i] = post_w[i]; u_p[i] = 0.f; }
        for (int m = 0; m < KNN; ++m) {
            int pi = pre_indices[qi * KNN + m];
            float pwm = pre_weights[qi * KNN + m];
            int f = -1;
            for (int s2 = 0; s2 < cnt2; ++s2) if (u_idx[s2] == pi) { f = s2; break; }
            if (f >= 0) u_p[f] = pwm;
            else { u_idx[cnt2] = pi; u_p[cnt2] = pwm; u_q[cnt2] = 0.f; ++cnt2; }
        }
        float Zp = 0.f, Zq = 0.f;
        for (int s2 = 0; s2 < cnt2; ++s2) { Zp += fmaxf(u_p[s2], EPSC); Zq += fmaxf(u_q[s2], EPSC); }
        float kl = 0.f;
        float izp = 1.f / Zp, izq = 1.f / Zq;
        for (int s2 = 0; s2 < cnt2; ++s2) {
            float pp = fmaxf(u_p[s2], EPSC) * izp;
            float qv = fmaxf(u_q[s2], EPSC) * izq;
            kl += pp * (logf(pp) - logf(qv));
        }
        kl_out[q] = kl;
    }
}

// ---------------- Kernel E: final reduction + outputs ----------------
__global__ void k_out(const float* __restrict__ kl, const float* __restrict__ W,
                      float* __restrict__ out) {
    int t = threadIdx.x;
    float s_kl = (t < BQ) ? kl[t] : 0.f;
    float s_w = 0.f;
    for (int i = t; i < DIM * DIM; i += 256) { float w = W[i]; s_w = fmaf(w, w, s_w); }
#pragma unroll
    for (int m = 32; m >= 1; m >>= 1) {
        s_kl += __shfl_xor(s_kl, m, 64);
        s_w += __shfl_xor(s_w, m, 64);
    }
    __shared__ float rk[4], rw[4];
    if ((t & 63) == 0) { rk[t >> 6] = s_kl; rw[t >> 6] = s_w; }
    __syncthreads();
    if (t == 0) {
        float kls = rk[0] + rk[1] + rk[2] + rk[3];
        float wss = rw[0] + rw[1] + rw[2] + rw[3];
        float knn = kls * (1.0f / BQ);
        float reg = 0.5f * wss;
        out[0] = 1.0f * knn + 1e-4f * reg;
        out[1] = 0.f;
        out[2] = knn;
    }
}

extern "C" void kernel_launch(void* const* d_in, const int* in_sizes, int n_in,
                              void* d_out, int out_size, void* d_ws, size_t ws_size,
                              hipStream_t stream) {
    const float* q_batch     = (const float*)d_in[0];
    const int*   q_indices   = (const int*)d_in[1];
    const float* X           = (const float*)d_in[2];
    const float* W           = (const float*)d_in[3];
    const int*   pre_indices = (const int*)d_in[4];
    const float* pre_weights = (const float*)d_in[5];

    float* ws = (float*)d_ws;
    float*  Tq  = ws;                                  // 32768 f32
    ushort* Tqb = (ushort*)(ws + 32768);               // 32768 bf16 (16384 f32 slots)
    float*  xsq = ws + 32768 + 16384;                  // 100000
    float*  klv = xsq + NDB;                           // 256
    ushort* Xbf = (ushort*)(klv + BQ);                 // 100000*128 bf16 = 25.6MB
    float*  cand_d = (float*)(Xbf + (size_t)NDB * DIM);
    int*    cand_i = (int*)(cand_d + (size_t)BQ * NBLK * KNN);

    k_tq<<<dim3(BQ), dim3(DIM), 0, stream>>>(q_batch, W, Tq, Tqb);
    k_xbf<<<dim3(NDB * 16 / 256), dim3(256), 0, stream>>>(X, Xbf, xsq);
    k_dist<<<dim3(NBLK), dim3(256), 0, stream>>>(Tqb, Xbf, xsq, cand_d, cand_i);
    k_final<<<dim3(BQ), dim3(256), 0, stream>>>(Tq, X, cand_d, cand_i,
                                                q_indices, pre_indices, pre_weights, klv);
    k_out<<<dim3(1), dim3(256), 0, stream>>>(klv, W, (float*)d_out);
}

// Round 4
// 221.872 us; speedup vs baseline: 1.7788x; 1.3908x over previous
//
#include <hip/hip_runtime.h>
#include <hip/hip_fp16.h>
#include <math.h>

#define KNN 16
#define DIM 128
#define BQ 256
#define NDB 100000
#define NDB_PAD 100096           // 391 * 256
#define NC 256                   // db rows per block
#define NBLK 391
#define RPP 32                   // rows per phase
#define NPH (NC / RPP)           // 8
#define XB_STR 136               // ushorts per LDS B-row (128 + 8 pad)
#define STRQ 264                 // padded query stride in dist LDS (f32)
#define TAU_INV 10.0f
#define EPSC 1e-8f
#define FBIG 3.402823e38f

typedef float f32x4 __attribute__((ext_vector_type(4)));
typedef __bf16 bf16x8 __attribute__((ext_vector_type(8)));
typedef unsigned short ushort;
typedef ushort ushort8 __attribute__((ext_vector_type(8)));

__device__ __forceinline__ ushort f32_to_bf16_rne(float v) {
    unsigned bits = __float_as_uint(v);
    return (ushort)((bits + 0x7FFFu + ((bits >> 16) & 1u)) >> 16);
}

// ---------------- Kernel A: Tq = q_batch @ W (f32 + bf16 copies) ----------------
__global__ void k_tq(const float* __restrict__ qb, const float* __restrict__ W,
                     float* __restrict__ Tq, ushort* __restrict__ Tqb) {
    int b = blockIdx.x, c = threadIdx.x;   // 128 threads
    __shared__ float qs[DIM];
    qs[c] = qb[b * DIM + c];
    __syncthreads();
    float acc = 0.f;
#pragma unroll 8
    for (int k = 0; k < DIM; ++k) acc = fmaf(qs[k], W[k * DIM + c], acc);
    Tq[b * DIM + c] = acc;
    Tqb[b * DIM + c] = f32_to_bf16_rne(acc);
}

// ---------------- Kernel B: pure MFMA distance GEMM -> fp16 dist[q][j] ----------------
// 391 blocks x 256 threads. X f32 read directly; bf16 convert + xsq during staging.
__global__ __launch_bounds__(256, 2)
void k_dist(const ushort* __restrict__ Tqb, const float* __restrict__ X,
            __half* __restrict__ distq) {
    __shared__ ushort xb[2][RPP * XB_STR];   // 2 x 8.5KB bf16 tiles (padded rows)
    __shared__ float xsq_lds[2][RPP];
    __shared__ float dist_lds[RPP * STRQ];   // 33.8KB [row][query]
    const int t = threadIdx.x;
    const int w = t >> 6;          // wave -> queries [64w, 64w+64)
    const int lane = t & 63;
    const int la = lane >> 4;      // 0..3
    const int lb = lane & 15;      // 0..15
    const int sr = t >> 3;         // staged row 0..31
    const int sc = t & 7;          // staged 16-dim chunk 0..7
    const int j0 = blockIdx.x * NC;

    // A fragments: 64 queries x K=128 (row = lane&15, k = (lane>>4)*8 + ks*32)
    bf16x8 afr[4][4];
#pragma unroll
    for (int mt = 0; mt < 4; ++mt)
#pragma unroll
        for (int ks = 0; ks < 4; ++ks)
            afr[mt][ks] = *reinterpret_cast<const bf16x8*>(
                Tqb + (size_t)(w * 64 + mt * 16 + lb) * DIM + ks * 32 + la * 8);

    // prolog: stage tile 0 (f32 -> bf16 + xsq)
    {
        int j = j0 + sr; int jc = (j < NDB) ? j : (NDB - 1);
        const float4* src = reinterpret_cast<const float4*>(X + (size_t)jc * DIM + sc * 16);
        float4 v0 = src[0], v1 = src[1], v2 = src[2], v3 = src[3];
        ushort8 o0, o1;
        o0[0]=f32_to_bf16_rne(v0.x); o0[1]=f32_to_bf16_rne(v0.y); o0[2]=f32_to_bf16_rne(v0.z); o0[3]=f32_to_bf16_rne(v0.w);
        o0[4]=f32_to_bf16_rne(v1.x); o0[5]=f32_to_bf16_rne(v1.y); o0[6]=f32_to_bf16_rne(v1.z); o0[7]=f32_to_bf16_rne(v1.w);
        o1[0]=f32_to_bf16_rne(v2.x); o1[1]=f32_to_bf16_rne(v2.y); o1[2]=f32_to_bf16_rne(v2.z); o1[3]=f32_to_bf16_rne(v2.w);
        o1[4]=f32_to_bf16_rne(v3.x); o1[5]=f32_to_bf16_rne(v3.y); o1[6]=f32_to_bf16_rne(v3.z); o1[7]=f32_to_bf16_rne(v3.w);
        *reinterpret_cast<ushort8*>(&xb[0][sr * XB_STR + sc * 16]) = o0;
        *reinterpret_cast<ushort8*>(&xb[0][sr * XB_STR + sc * 16 + 8]) = o1;
        float s = v0.x*v0.x + v0.y*v0.y + v0.z*v0.z + v0.w*v0.w
                + v1.x*v1.x + v1.y*v1.y + v1.z*v1.z + v1.w*v1.w
                + v2.x*v2.x + v2.y*v2.y + v2.z*v2.z + v2.w*v2.w
                + v3.x*v3.x + v3.y*v3.y + v3.z*v3.z + v3.w*v3.w;
        s += __shfl_xor(s, 1, 8); s += __shfl_xor(s, 2, 8); s += __shfl_xor(s, 4, 8);
        if (sc == 0) xsq_lds[0][sr] = s;
    }

    for (int ph = 0; ph < NPH; ++ph) {
        const int cur = ph & 1, nxt = cur ^ 1;
        const int rbase = j0 + ph * RPP;
        // prefetch next tile (f32) into regs
        float4 p0, p1, p2, p3;
        if (ph + 1 < NPH) {
            int j = rbase + RPP + sr; int jc = (j < NDB) ? j : (NDB - 1);
            const float4* src = reinterpret_cast<const float4*>(X + (size_t)jc * DIM + sc * 16);
            p0 = src[0]; p1 = src[1]; p2 = src[2]; p3 = src[3];
        }
        asm volatile("s_waitcnt lgkmcnt(0)" ::: "memory");
        __builtin_amdgcn_s_barrier();            // xb[cur]/xsq[cur] ready

        // compute: 2 n-tiles x 4 m-tiles x K=128
#pragma unroll
        for (int nt = 0; nt < 2; ++nt) {
            const int row = nt * 16 + lb;
            bf16x8 bfr[4];
#pragma unroll
            for (int ks = 0; ks < 4; ++ks)
                bfr[ks] = *reinterpret_cast<const bf16x8*>(
                    &xb[cur][row * XB_STR + ks * 32 + la * 8]);
            const float xs = xsq_lds[cur][row];
#pragma unroll
            for (int mt = 0; mt < 4; ++mt) {
                f32x4 acc = {0.f, 0.f, 0.f, 0.f};
#pragma unroll
                for (int ks = 0; ks < 4; ++ks)
                    acc = __builtin_amdgcn_mfma_f32_16x16x32_bf16(afr[mt][ks], bfr[ks], acc, 0, 0, 0);
                f32x4 val;
#pragma unroll
                for (int r = 0; r < 4; ++r) val[r] = xs - 2.f * acc[r];
                // C/D: col = lane&15 (db row), row = (lane>>4)*4 + r (query)
                *reinterpret_cast<f32x4*>(&dist_lds[row * STRQ + w * 64 + mt * 16 + la * 4]) = val;
            }
        }
        asm volatile("s_waitcnt lgkmcnt(0)" ::: "memory");
        __builtin_amdgcn_s_barrier();            // dist_lds ready

        // pack & store: thread t owns query t, 32 rows -> fp16, one 64B store
        {
            unsigned pk[16];
#pragma unroll
            for (int n = 0; n < 16; ++n) {
                float f0 = dist_lds[(2 * n) * STRQ + t];
                float f1 = dist_lds[(2 * n + 1) * STRQ + t];
                if (rbase + 2 * n >= NDB) f0 = FBIG;       // -> +inf fp16
                if (rbase + 2 * n + 1 >= NDB) f1 = FBIG;
                __half2 hh; hh.x = __float2half(f0); hh.y = __float2half(f1);
                pk[n] = *reinterpret_cast<unsigned*>(&hh);
            }
            uint4* dst = reinterpret_cast<uint4*>(distq + (size_t)t * NDB_PAD + rbase);
            uint4 o0, o1, o2, o3;
            o0.x=pk[0];  o0.y=pk[1];  o0.z=pk[2];  o0.w=pk[3];
            o1.x=pk[4];  o1.y=pk[5];  o1.z=pk[6];  o1.w=pk[7];
            o2.x=pk[8];  o2.y=pk[9];  o2.z=pk[10]; o2.w=pk[11];
            o3.x=pk[12]; o3.y=pk[13]; o3.z=pk[14]; o3.w=pk[15];
            dst[0]=o0; dst[1]=o1; dst[2]=o2; dst[3]=o3;
        }
        __builtin_amdgcn_s_barrier();            // dist_lds free

        if (ph + 1 < NPH) {                      // write-late: stage next tile
            ushort8 o0, o1;
            o0[0]=f32_to_bf16_rne(p0.x); o0[1]=f32_to_bf16_rne(p0.y); o0[2]=f32_to_bf16_rne(p0.z); o0[3]=f32_to_bf16_rne(p0.w);
            o0[4]=f32_to_bf16_rne(p1.x); o0[5]=f32_to_bf16_rne(p1.y); o0[6]=f32_to_bf16_rne(p1.z); o0[7]=f32_to_bf16_rne(p1.w);
            o1[0]=f32_to_bf16_rne(p2.x); o1[1]=f32_to_bf16_rne(p2.y); o1[2]=f32_to_bf16_rne(p2.z); o1[3]=f32_to_bf16_rne(p2.w);
            o1[4]=f32_to_bf16_rne(p3.x); o1[5]=f32_to_bf16_rne(p3.y); o1[6]=f32_to_bf16_rne(p3.z); o1[7]=f32_to_bf16_rne(p3.w);
            *reinterpret_cast<ushort8*>(&xb[nxt][sr * XB_STR + sc * 16]) = o0;
            *reinterpret_cast<ushort8*>(&xb[nxt][sr * XB_STR + sc * 16 + 8]) = o1;
            float s = p0.x*p0.x + p0.y*p0.y + p0.z*p0.z + p0.w*p0.w
                    + p1.x*p1.x + p1.y*p1.y + p1.z*p1.z + p1.w*p1.w
                    + p2.x*p2.x + p2.y*p2.y + p2.z*p2.z + p2.w*p2.w
                    + p3.x*p3.x + p3.y*p3.y + p3.z*p3.z + p3.w*p3.w;
            s += __shfl_xor(s, 1, 8); s += __shfl_xor(s, 2, 8); s += __shfl_xor(s, 4, 8);
            if (sc == 0) xsq_lds[nxt][sr] = s;
        }
    }
}

// ---------------- Kernel C: wave-cooperative global top-16 + exact l2 + KL ----------------
__global__ void k_sel(const __half* __restrict__ distq, const float* __restrict__ Tq,
                      const float* __restrict__ X,
                      const int* __restrict__ q_indices,
                      const int* __restrict__ pre_indices,
                      const float* __restrict__ pre_weights,
                      float* __restrict__ kl_out) {
    const int q = blockIdx.x, t = threadIdx.x, w = t >> 6, lane = t & 63;
    __shared__ float sd[64]; __shared__ int si[64];
    __shared__ int post_idx[KNN];
    __shared__ float l2s[KNN];
    __shared__ float post_w[KNN];
    __shared__ int u_idx[2 * KNN]; __shared__ float u_p[2 * KNN]; __shared__ float u_q[2 * KNN];

    const __half* dq = distq + (size_t)q * NDB_PAD;
    // lane-distributed sorted top-16 (ascending), replicated per 16-lane subgroup
    float td = FBIG; int ti = -1; float tau = FBIG;
    const int base = w * (NDB_PAD / 4);          // 25024 per wave
    for (int i = 0; i < NDB_PAD / 256; ++i) {    // 391 iters
        int j = base + i * 64 + lane;
        float dv = __half2float(dq[j]);
        unsigned long long mask = __ballot(dv < tau);
        while (mask) {
            int src = __builtin_ctzll(mask); mask &= mask - 1;
            float v = __shfl(dv, src);
            int vj = __shfl(j, src);
            if (v < tau) {                        // wave-uniform branch
                float tp = __shfl_up(td, 1, 16);
                int   ip = __shfl_up(ti, 1, 16);
                if ((lane & 15) == 0) tp = -FBIG;
                bool c1 = v < td, c2 = v < tp;
                td = c1 ? (c2 ? tp : v) : td;
                ti = c1 ? (c2 ? ip : vj) : ti;
                tau = __shfl(td, 15, 16);
            }
        }
    }
    if (lane < 16) { sd[w * 16 + lane] = td; si[w * 16 + lane] = ti; }
    __syncthreads();

    if (t == 0) {   // 4-way merge of the 4 sorted wave lists
        int p[4] = {0, 0, 0, 0};
        for (int o = 0; o < KNN; ++o) {
            float best = FBIG; int bw = 0;
#pragma unroll
            for (int m2 = 0; m2 < 4; ++m2) {
                if (p[m2] < KNN) { float v = sd[m2 * 16 + p[m2]]; if (v < best) { best = v; bw = m2; } }
            }
            post_idx[o] = si[bw * 16 + p[bw]]; ++p[bw];
        }
    }
    __syncthreads();

    {   // exact f32 l2 for the selected 16 (16 threads x 8 dims each)
        int n = t >> 4, l = t & 15;
        int idx = post_idx[n];
        const float* tr = Tq + q * DIM + l * 8;
        const float* xr = X + (size_t)idx * DIM + l * 8;
        float s = 0.f;
#pragma unroll
        for (int kk = 0; kk < 8; ++kk) { float df = tr[kk] - xr[kk]; s = fmaf(df, df, s); }
#pragma unroll
        for (int m = 1; m < 16; m <<= 1) s += __shfl_xor(s, m, 64);
        if (l == 0) l2s[n] = s;
    }
    __syncthreads();

    if (t == 0) {
        float mx = -FBIG;
        for (int i = 0; i < KNN; ++i) { float v = -l2s[i] * TAU_INV; post_w[i] = v; if (v > mx) mx = v; }
        float sum = 0.f;
        for (int i = 0; i < KNN; ++i) { float e = expf(post_w[i] - mx); post_w[i] = e; sum += e; }
        float inv = 1.f / sum;
        for (int i = 0; i < KNN; ++i) post_w[i] *= inv;

        int qi = q_indices[q];
        int cnt2 = KNN;
        for (int i = 0; i < KNN; ++i) { u_idx[i] = post_idx[i]; u_q[i] = post_w[i]; u_p[i] = 0.f; }
        for (int m = 0; m < KNN; ++m) {
            int pi = pre_indices[qi * KNN + m];
            float pwm = pre_weights[qi * KNN + m];
            int f = -1;
            for (int s2 = 0; s2 < cnt2; ++s2) if (u_idx[s2] == pi) { f = s2; break; }
            if (f >= 0) u_p[f] = pwm;
            else { u_idx[cnt2] = pi; u_p[cnt2] = pwm; u_q[cnt2] = 0.f; ++cnt2; }
        }
        float Zp = 0.f, Zq = 0.f;
        for (int s2 = 0; s2 < cnt2; ++s2) { Zp += fmaxf(u_p[s2], EPSC); Zq += fmaxf(u_q[s2], EPSC); }
        float kl = 0.f;
        float izp = 1.f / Zp, izq = 1.f / Zq;
        for (int s2 = 0; s2 < cnt2; ++s2) {
            float pp = fmaxf(u_p[s2], EPSC) * izp;
            float qv = fmaxf(u_q[s2], EPSC) * izq;
            kl += pp * (logf(pp) - logf(qv));
        }
        kl_out[q] = kl;
    }
}

// ---------------- Kernel D: final reduction + outputs ----------------
__global__ void k_out(const float* __restrict__ kl, const float* __restrict__ W,
                      float* __restrict__ out) {
    int t = threadIdx.x;
    float s_kl = (t < BQ) ? kl[t] : 0.f;
    float s_w = 0.f;
    for (int i = t; i < DIM * DIM; i += 256) { float w = W[i]; s_w = fmaf(w, w, s_w); }
#pragma unroll
    for (int m = 32; m >= 1; m >>= 1) {
        s_kl += __shfl_xor(s_kl, m, 64);
        s_w += __shfl_xor(s_w, m, 64);
    }
    __shared__ float rk[4], rw[4];
    if ((t & 63) == 0) { rk[t >> 6] = s_kl; rw[t >> 6] = s_w; }
    __syncthreads();
    if (t == 0) {
        float kls = rk[0] + rk[1] + rk[2] + rk[3];
        float wss = rw[0] + rw[1] + rw[2] + rw[3];
        float knn = kls * (1.0f / BQ);
        float reg = 0.5f * wss;
        out[0] = 1.0f * knn + 1e-4f * reg;
        out[1] = 0.f;
        out[2] = knn;
    }
}

extern "C" void kernel_launch(void* const* d_in, const int* in_sizes, int n_in,
                              void* d_out, int out_size, void* d_ws, size_t ws_size,
                              hipStream_t stream) {
    const float* q_batch     = (const float*)d_in[0];
    const int*   q_indices   = (const int*)d_in[1];
    const float* X           = (const float*)d_in[2];
    const float* W           = (const float*)d_in[3];
    const int*   pre_indices = (const int*)d_in[4];
    const float* pre_weights = (const float*)d_in[5];

    char* ws = (char*)d_ws;
    float*  Tq    = (float*)(ws);                 // 128KB
    ushort* Tqb   = (ushort*)(ws + 131072);       // 64KB
    float*  klv   = (float*)(ws + 196608);        // 1KB
    __half* distq = (__half*)(ws + 262144);       // 256 * 100096 fp16 = 51.25MB

    k_tq<<<dim3(BQ), dim3(DIM), 0, stream>>>(q_batch, W, Tq, Tqb);
    k_dist<<<dim3(NBLK), dim3(256), 0, stream>>>(Tqb, X, distq);
    k_sel<<<dim3(BQ), dim3(256), 0, stream>>>(distq, Tq, X,
                                              q_indices, pre_indices, pre_weights, klv);
    k_out<<<dim3(1), dim3(256), 0, stream>>>(klv, W, (float*)d_out);
}

// Round 6
// 136.161 us; speedup vs baseline: 2.8985x; 1.6295x over previous
//
#include <hip/hip_runtime.h>
#include <hip/hip_fp16.h>
#include <math.h>

#define KNN 16
#define DIM 128
#define BQ 256
#define NDB 100000
#define NDB_PAD 100096           // 391 * 256
#define NC 256                   // db rows per block
#define NBLK 391
#define RPP 32                   // rows per phase
#define NPH (NC / RPP)           // 8
#define XB_STR 136               // ushorts per LDS B-row (128 + 8 pad)
#define STRQ 264                 // padded query stride in dist LDS (f32)
#define WSLICE 12512             // NDB_PAD / 8 waves
#define WQ4 1564                 // WSLICE / 8 halves per uint4
#define NIT 25                   // ceil(1564 / 64)
#define TAU_INV 10.0f
#define EPSC 1e-8f
#define FBIG 3.402823e38f
#define HINF4 0x7C007C00u

typedef float f32x4 __attribute__((ext_vector_type(4)));
typedef __bf16 bf16x8 __attribute__((ext_vector_type(8)));
typedef unsigned short ushort;
typedef ushort ushort8 __attribute__((ext_vector_type(8)));

__device__ __forceinline__ ushort f32_to_bf16_rne(float v) {
    unsigned bits = __float_as_uint(v);
    return (ushort)((bits + 0x7FFFu + ((bits >> 16) & 1u)) >> 16);
}
__device__ __forceinline__ __half2 u2h(unsigned u) {
    __half2 h; *reinterpret_cast<unsigned*>(&h) = u; return h;
}

// ---------------- Kernel A: Tq = q_batch @ W (f32 + bf16 copies) ----------------
__global__ void k_tq(const float* __restrict__ qb, const float* __restrict__ W,
                     float* __restrict__ Tq, ushort* __restrict__ Tqb) {
    int b = blockIdx.x, c = threadIdx.x;   // 128 threads
    __shared__ float qs[DIM];
    qs[c] = qb[b * DIM + c];
    __syncthreads();
    float acc = 0.f;
#pragma unroll 8
    for (int k = 0; k < DIM; ++k) acc = fmaf(qs[k], W[k * DIM + c], acc);
    Tq[b * DIM + c] = acc;
    Tqb[b * DIM + c] = f32_to_bf16_rne(acc);
}

// ---------------- Kernel B: pure MFMA distance GEMM -> fp16 dist[q][j] ----------------
__global__ __launch_bounds__(256, 2)
void k_dist(const ushort* __restrict__ Tqb, const float* __restrict__ X,
            __half* __restrict__ distq) {
    __shared__ ushort xb[2][RPP * XB_STR];   // 2 x 8.5KB bf16 tiles (padded rows)
    __shared__ float xsq_lds[2][RPP];
    __shared__ float dist_lds[RPP * STRQ];   // 33.8KB [row][query]
    const int t = threadIdx.x;
    const int w = t >> 6;          // wave -> queries [64w, 64w+64)
    const int lane = t & 63;
    const int la = lane >> 4;      // 0..3
    const int lb = lane & 15;      // 0..15
    const int sr = t >> 3;         // staged row 0..31
    const int sc = t & 7;          // staged 16-dim chunk 0..7
    const int j0 = blockIdx.x * NC;

    bf16x8 afr[4][4];
#pragma unroll
    for (int mt = 0; mt < 4; ++mt)
#pragma unroll
        for (int ks = 0; ks < 4; ++ks)
            afr[mt][ks] = *reinterpret_cast<const bf16x8*>(
                Tqb + (size_t)(w * 64 + mt * 16 + lb) * DIM + ks * 32 + la * 8);

    {   // prolog: stage tile 0
        int j = j0 + sr; int jc = (j < NDB) ? j : (NDB - 1);
        const float4* src = reinterpret_cast<const float4*>(X + (size_t)jc * DIM + sc * 16);
        float4 v0 = src[0], v1 = src[1], v2 = src[2], v3 = src[3];
        ushort8 o0, o1;
        o0[0]=f32_to_bf16_rne(v0.x); o0[1]=f32_to_bf16_rne(v0.y); o0[2]=f32_to_bf16_rne(v0.z); o0[3]=f32_to_bf16_rne(v0.w);
        o0[4]=f32_to_bf16_rne(v1.x); o0[5]=f32_to_bf16_rne(v1.y); o0[6]=f32_to_bf16_rne(v1.z); o0[7]=f32_to_bf16_rne(v1.w);
        o1[0]=f32_to_bf16_rne(v2.x); o1[1]=f32_to_bf16_rne(v2.y); o1[2]=f32_to_bf16_rne(v2.z); o1[3]=f32_to_bf16_rne(v2.w);
        o1[4]=f32_to_bf16_rne(v3.x); o1[5]=f32_to_bf16_rne(v3.y); o1[6]=f32_to_bf16_rne(v3.z); o1[7]=f32_to_bf16_rne(v3.w);
        *reinterpret_cast<ushort8*>(&xb[0][sr * XB_STR + sc * 16]) = o0;
        *reinterpret_cast<ushort8*>(&xb[0][sr * XB_STR + sc * 16 + 8]) = o1;
        float s = v0.x*v0.x + v0.y*v0.y + v0.z*v0.z + v0.w*v0.w
                + v1.x*v1.x + v1.y*v1.y + v1.z*v1.z + v1.w*v1.w
                + v2.x*v2.x + v2.y*v2.y + v2.z*v2.z + v2.w*v2.w
                + v3.x*v3.x + v3.y*v3.y + v3.z*v3.z + v3.w*v3.w;
        s += __shfl_xor(s, 1, 8); s += __shfl_xor(s, 2, 8); s += __shfl_xor(s, 4, 8);
        if (sc == 0) xsq_lds[0][sr] = s;
    }

    for (int ph = 0; ph < NPH; ++ph) {
        const int cur = ph & 1, nxt = cur ^ 1;
        const int rbase = j0 + ph * RPP;
        float4 p0, p1, p2, p3;
        if (ph + 1 < NPH) {
            int j = rbase + RPP + sr; int jc = (j < NDB) ? j : (NDB - 1);
            const float4* src = reinterpret_cast<const float4*>(X + (size_t)jc * DIM + sc * 16);
            p0 = src[0]; p1 = src[1]; p2 = src[2]; p3 = src[3];
        }
        asm volatile("s_waitcnt lgkmcnt(0)" ::: "memory");
        __builtin_amdgcn_s_barrier();            // xb[cur]/xsq[cur] ready

#pragma unroll
        for (int nt = 0; nt < 2; ++nt) {
            const int row = nt * 16 + lb;
            bf16x8 bfr[4];
#pragma unroll
            for (int ks = 0; ks < 4; ++ks)
                bfr[ks] = *reinterpret_cast<const bf16x8*>(
                    &xb[cur][row * XB_STR + ks * 32 + la * 8]);
            const float xs = xsq_lds[cur][row];
#pragma unroll
            for (int mt = 0; mt < 4; ++mt) {
                f32x4 acc = {0.f, 0.f, 0.f, 0.f};
#pragma unroll
                for (int ks = 0; ks < 4; ++ks)
                    acc = __builtin_amdgcn_mfma_f32_16x16x32_bf16(afr[mt][ks], bfr[ks], acc, 0, 0, 0);
                f32x4 val;
#pragma unroll
                for (int r = 0; r < 4; ++r) val[r] = xs - 2.f * acc[r];
                *reinterpret_cast<f32x4*>(&dist_lds[row * STRQ + w * 64 + mt * 16 + la * 4]) = val;
            }
        }
        asm volatile("s_waitcnt lgkmcnt(0)" ::: "memory");
        __builtin_amdgcn_s_barrier();            // dist_lds ready

        {   // pack & store: thread t owns query t
            unsigned pk[16];
#pragma unroll
            for (int n = 0; n < 16; ++n) {
                float f0 = dist_lds[(2 * n) * STRQ + t];
                float f1 = dist_lds[(2 * n + 1) * STRQ + t];
                if (rbase + 2 * n >= NDB) f0 = FBIG;
                if (rbase + 2 * n + 1 >= NDB) f1 = FBIG;
                __half2 hh; hh.x = __float2half(f0); hh.y = __float2half(f1);
                pk[n] = *reinterpret_cast<unsigned*>(&hh);
            }
            uint4* dst = reinterpret_cast<uint4*>(distq + (size_t)t * NDB_PAD + rbase);
            uint4 o0, o1, o2, o3;
            o0.x=pk[0];  o0.y=pk[1];  o0.z=pk[2];  o0.w=pk[3];
            o1.x=pk[4];  o1.y=pk[5];  o1.z=pk[6];  o1.w=pk[7];
            o2.x=pk[8];  o2.y=pk[9];  o2.z=pk[10]; o2.w=pk[11];
            o3.x=pk[12]; o3.y=pk[13]; o3.z=pk[14]; o3.w=pk[15];
            dst[0]=o0; dst[1]=o1; dst[2]=o2; dst[3]=o3;
        }
        __builtin_amdgcn_s_barrier();            // dist_lds free

        if (ph + 1 < NPH) {
            ushort8 o0, o1;
            o0[0]=f32_to_bf16_rne(p0.x); o0[1]=f32_to_bf16_rne(p0.y); o0[2]=f32_to_bf16_rne(p0.z); o0[3]=f32_to_bf16_rne(p0.w);
            o0[4]=f32_to_bf16_rne(p1.x); o0[5]=f32_to_bf16_rne(p1.y); o0[6]=f32_to_bf16_rne(p1.z); o0[7]=f32_to_bf16_rne(p1.w);
            o1[0]=f32_to_bf16_rne(p2.x); o1[1]=f32_to_bf16_rne(p2.y); o1[2]=f32_to_bf16_rne(p2.z); o1[3]=f32_to_bf16_rne(p2.w);
            o1[4]=f32_to_bf16_rne(p3.x); o1[5]=f32_to_bf16_rne(p3.y); o1[6]=f32_to_bf16_rne(p3.z); o1[7]=f32_to_bf16_rne(p3.w);
            *reinterpret_cast<ushort8*>(&xb[nxt][sr * XB_STR + sc * 16]) = o0;
            *reinterpret_cast<ushort8*>(&xb[nxt][sr * XB_STR + sc * 16 + 8]) = o1;
            float s = p0.x*p0.x + p0.y*p0.y + p0.z*p0.z + p0.w*p0.w
                    + p1.x*p1.x + p1.y*p1.y + p1.z*p1.z + p1.w*p1.w
                    + p2.x*p2.x + p2.y*p2.y + p2.z*p2.z + p2.w*p2.w
                    + p3.x*p3.x + p3.y*p3.y + p3.z*p3.z + p3.w*p3.w;
            s += __shfl_xor(s, 1, 8); s += __shfl_xor(s, 2, 8); s += __shfl_xor(s, 4, 8);
            if (sc == 0) xsq_lds[nxt][sr] = s;
        }
    }
}

// ---------------- Kernel C: vectorized pipelined global top-16 + exact l2 + KL ----------------
__global__ __launch_bounds__(512)
void k_sel(const __half* __restrict__ distq, const float* __restrict__ Tq,
           const float* __restrict__ X,
           const int* __restrict__ q_indices,
           const int* __restrict__ pre_indices,
           const float* __restrict__ pre_weights,
           float* __restrict__ kl_out) {
    const int q = blockIdx.x, t = threadIdx.x, w = t >> 6, lane = t & 63;
    __shared__ float sd[128]; __shared__ int si[128];
    __shared__ int post_idx[KNN];
    __shared__ float l2s[KNN];
    __shared__ float post_w[KNN];
    __shared__ int u_idx[2 * KNN]; __shared__ float u_p[2 * KNN]; __shared__ float u_q[2 * KNN];

    const __half* dq = distq + (size_t)q * NDB_PAD;
    const uint4* src = reinterpret_cast<const uint4*>(dq) + w * WQ4;
    const int jbase = w * WSLICE;

    // per-16-lane-group replicated sorted top-16 (ascending)
    float td = FBIG; int ti = -1; float tau = FBIG;

#define LOADI(dst, i)                                                     \
    {   int idx_ = (i) * 64 + lane;                                       \
        dst = src[idx_ < WQ4 ? idx_ : WQ4 - 1];                           \
        if (idx_ >= WQ4) { dst.x = dst.y = dst.z = dst.w = HINF4; } }

    uint4 c0, c1;
    LOADI(c0, 0); LOADI(c1, 1);
    for (int i = 0; i < NIT; ++i) {
        uint4 c2;
        if (i + 2 < NIT) { LOADI(c2, i + 2); }
        else { c2.x = c2.y = c2.z = c2.w = HINF4; }
        // convert 8 fp16 -> f32, min-tree filter (f32; no packed-half intrinsics)
        float fl0, fl1, fl2, fl3, fl4, fl5, fl6, fl7;
        {
            __half2 hh;
            hh = u2h(c0.x); fl0 = __half2float(__low2half(hh)); fl1 = __half2float(__high2half(hh));
            hh = u2h(c0.y); fl2 = __half2float(__low2half(hh)); fl3 = __half2float(__high2half(hh));
            hh = u2h(c0.z); fl4 = __half2float(__low2half(hh)); fl5 = __half2float(__high2half(hh));
            hh = u2h(c0.w); fl6 = __half2float(__low2half(hh)); fl7 = __half2float(__high2half(hh));
        }
        float fmn = fminf(fminf(fminf(fl0, fl1), fminf(fl2, fl3)),
                          fminf(fminf(fl4, fl5), fminf(fl6, fl7)));
        unsigned long long hit = __ballot(fmn < tau);
        while (hit) {
            int s = __builtin_ctzll(hit); hit &= hit - 1;
            float f[8];
            f[0] = __shfl(fl0, s); f[1] = __shfl(fl1, s);
            f[2] = __shfl(fl2, s); f[3] = __shfl(fl3, s);
            f[4] = __shfl(fl4, s); f[5] = __shfl(fl5, s);
            f[6] = __shfl(fl6, s); f[7] = __shfl(fl7, s);
            int j8 = jbase + (i * 64 + s) * 8;
#pragma unroll
            for (int e = 0; e < 8; ++e) {
                float v = f[e];
                if (v < tau) {                        // wave-uniform
                    float tp = __shfl_up(td, 1, 16);
                    int   ip = __shfl_up(ti, 1, 16);
                    if ((lane & 15) == 0) tp = -FBIG;
                    bool A = v < td, B = v < tp;
                    td = A ? (B ? tp : v) : td;
                    ti = A ? (B ? ip : (j8 + e)) : ti;
                    tau = __shfl(td, 15, 16);
                }
            }
        }
        c0 = c1; c1 = c2;
    }
#undef LOADI

    if (lane < 16) { sd[w * 16 + lane] = td; si[w * 16 + lane] = ti; }
    __syncthreads();

    if (t == 0) {   // 8-way merge of sorted wave lists (constant-indexed p[])
        int p[8] = {0, 0, 0, 0, 0, 0, 0, 0};
        for (int o = 0; o < KNN; ++o) {
            float best = FBIG; int bw = 0;
#pragma unroll
            for (int m2 = 0; m2 < 8; ++m2) {
                float v = (p[m2] < KNN) ? sd[m2 * 16 + p[m2]] : FBIG;
                if (v < best) { best = v; bw = m2; }
            }
            post_idx[o] = si[bw * 16 + p[bw]];
#pragma unroll
            for (int m2 = 0; m2 < 8; ++m2) p[m2] += (m2 == bw) ? 1 : 0;
        }
    }
    __syncthreads();

    if (t < 256) {   // exact f32 l2 for the selected 16 (16 threads x 8 dims each)
        int n = t >> 4, l = t & 15;
        int idx = post_idx[n];
        const float* tr = Tq + q * DIM + l * 8;
        const float* xr = X + (size_t)idx * DIM + l * 8;
        float s = 0.f;
#pragma unroll
        for (int kk = 0; kk < 8; ++kk) { float df = tr[kk] - xr[kk]; s = fmaf(df, df, s); }
#pragma unroll
        for (int m = 1; m < 16; m <<= 1) s += __shfl_xor(s, m, 64);
        if (l == 0) l2s[n] = s;
    }
    __syncthreads();

    if (t == 0) {
        float mx = -FBIG;
        for (int i = 0; i < KNN; ++i) { float v = -l2s[i] * TAU_INV; post_w[i] = v; if (v > mx) mx = v; }
        float sum = 0.f;
        for (int i = 0; i < KNN; ++i) { float e = expf(post_w[i] - mx); post_w[i] = e; sum += e; }
        float inv = 1.f / sum;
        for (int i = 0; i < KNN; ++i) post_w[i] *= inv;

        int qi = q_indices[q];
        int cnt2 = KNN;
        for (int i = 0; i < KNN; ++i) { u_idx[i] = post_idx[i]; u_q[i] = post_w[i]; u_p[i] = 0.f; }
        for (int m = 0; m < KNN; ++m) {
            int pi = pre_indices[qi * KNN + m];
            float pwm = pre_weights[qi * KNN + m];
            int f = -1;
            for (int s2 = 0; s2 < cnt2; ++s2) if (u_idx[s2] == pi) { f = s2; break; }
            if (f >= 0) u_p[f] = pwm;
            else { u_idx[cnt2] = pi; u_p[cnt2] = pwm; u_q[cnt2] = 0.f; ++cnt2; }
        }
        float Zp = 0.f, Zq = 0.f;
        for (int s2 = 0; s2 < cnt2; ++s2) { Zp += fmaxf(u_p[s2], EPSC); Zq += fmaxf(u_q[s2], EPSC); }
        float kl = 0.f;
        float izp = 1.f / Zp, izq = 1.f / Zq;
        for (int s2 = 0; s2 < cnt2; ++s2) {
            float pp = fmaxf(u_p[s2], EPSC) * izp;
            float qv = fmaxf(u_q[s2], EPSC) * izq;
            kl += pp * (logf(pp) - logf(qv));
        }
        kl_out[q] = kl;
    }
}

// ---------------- Kernel D: final reduction + outputs ----------------
__global__ void k_out(const float* __restrict__ kl, const float* __restrict__ W,
                      float* __restrict__ out) {
    int t = threadIdx.x;
    float s_kl = (t < BQ) ? kl[t] : 0.f;
    float s_w = 0.f;
    for (int i = t; i < DIM * DIM; i += 256) { float w = W[i]; s_w = fmaf(w, w, s_w); }
#pragma unroll
    for (int m = 32; m >= 1; m >>= 1) {
        s_kl += __shfl_xor(s_kl, m, 64);
        s_w += __shfl_xor(s_w, m, 64);
    }
    __shared__ float rk[4], rw[4];
    if ((t & 63) == 0) { rk[t >> 6] = s_kl; rw[t >> 6] = s_w; }
    __syncthreads();
    if (t == 0) {
        float kls = rk[0] + rk[1] + rk[2] + rk[3];
        float wss = rw[0] + rw[1] + rw[2] + rw[3];
        float knn = kls * (1.0f / BQ);
        float reg = 0.5f * wss;
        out[0] = 1.0f * knn + 1e-4f * reg;
        out[1] = 0.f;
        out[2] = knn;
    }
}

extern "C" void kernel_launch(void* const* d_in, const int* in_sizes, int n_in,
                              void* d_out, int out_size, void* d_ws, size_t ws_size,
                              hipStream_t stream) {
    const float* q_batch     = (const float*)d_in[0];
    const int*   q_indices   = (const int*)d_in[1];
    const float* X           = (const float*)d_in[2];
    const float* W           = (const float*)d_in[3];
    const int*   pre_indices = (const int*)d_in[4];
    const float* pre_weights = (const float*)d_in[5];

    char* ws = (char*)d_ws;
    float*  Tq    = (float*)(ws);                 // 128KB
    ushort* Tqb   = (ushort*)(ws + 131072);       // 64KB
    float*  klv   = (float*)(ws + 196608);        // 1KB
    __half* distq = (__half*)(ws + 262144);       // 256 * 100096 fp16 = 51.25MB

    k_tq<<<dim3(BQ), dim3(DIM), 0, stream>>>(q_batch, W, Tq, Tqb);
    k_dist<<<dim3(NBLK), dim3(256), 0, stream>>>(Tqb, X, distq);
    k_sel<<<dim3(BQ), dim3(512), 0, stream>>>(distq, Tq, X,
                                              q_indices, pre_indices, pre_weights, klv);
    k_out<<<dim3(1), dim3(256), 0, stream>>>(klv, W, (float*)d_out);
}

// Round 7
// 101.272 us; speedup vs baseline: 3.8971x; 1.3445x over previous
//
#include <hip/hip_runtime.h>
#include <hip/hip_fp16.h>
#include <math.h>

#define KNN 16
#define DIM 128
#define BQ 256
#define NDB 100000
#define NDB_PAD 100096           // 391 * 256
#define NC 256                   // db rows per block
#define NBLK 391
#define RPP 32                   // rows per phase
#define NPH (NC / RPP)           // 8
#define XB_STR 136               // ushorts per LDS B-row (128 + 8 pad)
#define STRQ 264                 // padded query stride in dist LDS (f32)
#define WSLICE 12512             // NDB_PAD / 8 waves
#define WQ4 1564                 // WSLICE / 8 halves per uint4
#define NIT 25                   // ceil(1564 / 64)
#define CAP 4096                 // candidate buffer capacity
#define TAU_INV 10.0f
#define EPSC 1e-8f
#define FBIG 3.402823e38f
#define HINF4 0x7C007C00u

typedef float f32x4 __attribute__((ext_vector_type(4)));
typedef __bf16 bf16x8 __attribute__((ext_vector_type(8)));
typedef unsigned short ushort;
typedef ushort ushort8 __attribute__((ext_vector_type(8)));

__device__ __forceinline__ ushort f32_to_bf16_rne(float v) {
    unsigned bits = __float_as_uint(v);
    return (ushort)((bits + 0x7FFFu + ((bits >> 16) & 1u)) >> 16);
}
__device__ __forceinline__ __half2 u2h(unsigned u) {
    __half2 h; *reinterpret_cast<unsigned*>(&h) = u; return h;
}

// ---------------- Kernel A: Tq = q_batch @ W (f32 + bf16 copies) ----------------
__global__ void k_tq(const float* __restrict__ qb, const float* __restrict__ W,
                     float* __restrict__ Tq, ushort* __restrict__ Tqb) {
    int b = blockIdx.x, c = threadIdx.x;   // 128 threads
    __shared__ float qs[DIM];
    qs[c] = qb[b * DIM + c];
    __syncthreads();
    float acc = 0.f;
#pragma unroll 8
    for (int k = 0; k < DIM; ++k) acc = fmaf(qs[k], W[k * DIM + c], acc);
    Tq[b * DIM + c] = acc;
    Tqb[b * DIM + c] = f32_to_bf16_rne(acc);
}

// ---------------- Kernel B: MFMA distance GEMM -> fp16 dist[q][j] + per-(blk,q) min ----------------
__global__ __launch_bounds__(256, 2)
void k_dist(const ushort* __restrict__ Tqb, const float* __restrict__ X,
            __half* __restrict__ distq, float* __restrict__ blkmin) {
    __shared__ ushort xb[2][RPP * XB_STR];   // 2 x 8.5KB bf16 tiles (padded rows)
    __shared__ float xsq_lds[2][RPP];
    __shared__ float dist_lds[RPP * STRQ];   // 33.8KB [row][query]
    const int t = threadIdx.x;
    const int w = t >> 6;          // wave -> queries [64w, 64w+64)
    const int lane = t & 63;
    const int la = lane >> 4;      // 0..3
    const int lb = lane & 15;      // 0..15
    const int sr = t >> 3;         // staged row 0..31
    const int sc = t & 7;          // staged 16-dim chunk 0..7
    const int j0 = blockIdx.x * NC;

    bf16x8 afr[4][4];
#pragma unroll
    for (int mt = 0; mt < 4; ++mt)
#pragma unroll
        for (int ks = 0; ks < 4; ++ks)
            afr[mt][ks] = *reinterpret_cast<const bf16x8*>(
                Tqb + (size_t)(w * 64 + mt * 16 + lb) * DIM + ks * 32 + la * 8);

    {   // prolog: stage tile 0
        int j = j0 + sr; int jc = (j < NDB) ? j : (NDB - 1);
        const float4* src = reinterpret_cast<const float4*>(X + (size_t)jc * DIM + sc * 16);
        float4 v0 = src[0], v1 = src[1], v2 = src[2], v3 = src[3];
        ushort8 o0, o1;
        o0[0]=f32_to_bf16_rne(v0.x); o0[1]=f32_to_bf16_rne(v0.y); o0[2]=f32_to_bf16_rne(v0.z); o0[3]=f32_to_bf16_rne(v0.w);
        o0[4]=f32_to_bf16_rne(v1.x); o0[5]=f32_to_bf16_rne(v1.y); o0[6]=f32_to_bf16_rne(v1.z); o0[7]=f32_to_bf16_rne(v1.w);
        o1[0]=f32_to_bf16_rne(v2.x); o1[1]=f32_to_bf16_rne(v2.y); o1[2]=f32_to_bf16_rne(v2.z); o1[3]=f32_to_bf16_rne(v2.w);
        o1[4]=f32_to_bf16_rne(v3.x); o1[5]=f32_to_bf16_rne(v3.y); o1[6]=f32_to_bf16_rne(v3.z); o1[7]=f32_to_bf16_rne(v3.w);
        *reinterpret_cast<ushort8*>(&xb[0][sr * XB_STR + sc * 16]) = o0;
        *reinterpret_cast<ushort8*>(&xb[0][sr * XB_STR + sc * 16 + 8]) = o1;
        float s = v0.x*v0.x + v0.y*v0.y + v0.z*v0.z + v0.w*v0.w
                + v1.x*v1.x + v1.y*v1.y + v1.z*v1.z + v1.w*v1.w
                + v2.x*v2.x + v2.y*v2.y + v2.z*v2.z + v2.w*v2.w
                + v3.x*v3.x + v3.y*v3.y + v3.z*v3.z + v3.w*v3.w;
        s += __shfl_xor(s, 1, 8); s += __shfl_xor(s, 2, 8); s += __shfl_xor(s, 4, 8);
        if (sc == 0) xsq_lds[0][sr] = s;
    }

    float mnall = FBIG;   // running min of this thread's (query t) distances in this block

    for (int ph = 0; ph < NPH; ++ph) {
        const int cur = ph & 1, nxt = cur ^ 1;
        const int rbase = j0 + ph * RPP;
        float4 p0, p1, p2, p3;
        if (ph + 1 < NPH) {
            int j = rbase + RPP + sr; int jc = (j < NDB) ? j : (NDB - 1);
            const float4* src = reinterpret_cast<const float4*>(X + (size_t)jc * DIM + sc * 16);
            p0 = src[0]; p1 = src[1]; p2 = src[2]; p3 = src[3];
        }
        asm volatile("s_waitcnt lgkmcnt(0)" ::: "memory");
        __builtin_amdgcn_s_barrier();            // xb[cur]/xsq[cur] ready

#pragma unroll
        for (int nt = 0; nt < 2; ++nt) {
            const int row = nt * 16 + lb;
            bf16x8 bfr[4];
#pragma unroll
            for (int ks = 0; ks < 4; ++ks)
                bfr[ks] = *reinterpret_cast<const bf16x8*>(
                    &xb[cur][row * XB_STR + ks * 32 + la * 8]);
            const float xs = xsq_lds[cur][row];
#pragma unroll
            for (int mt = 0; mt < 4; ++mt) {
                f32x4 acc = {0.f, 0.f, 0.f, 0.f};
#pragma unroll
                for (int ks = 0; ks < 4; ++ks)
                    acc = __builtin_amdgcn_mfma_f32_16x16x32_bf16(afr[mt][ks], bfr[ks], acc, 0, 0, 0);
                f32x4 val;
#pragma unroll
                for (int r = 0; r < 4; ++r) val[r] = xs - 2.f * acc[r];
                *reinterpret_cast<f32x4*>(&dist_lds[row * STRQ + w * 64 + mt * 16 + la * 4]) = val;
            }
        }
        asm volatile("s_waitcnt lgkmcnt(0)" ::: "memory");
        __builtin_amdgcn_s_barrier();            // dist_lds ready

        {   // pack & store: thread t owns query t; track min
            unsigned pk[16];
#pragma unroll
            for (int n = 0; n < 16; ++n) {
                float f0 = dist_lds[(2 * n) * STRQ + t];
                float f1 = dist_lds[(2 * n + 1) * STRQ + t];
                if (rbase + 2 * n >= NDB) f0 = FBIG;
                if (rbase + 2 * n + 1 >= NDB) f1 = FBIG;
                mnall = fminf(mnall, fminf(f0, f1));
                __half2 hh; hh.x = __float2half(f0); hh.y = __float2half(f1);
                pk[n] = *reinterpret_cast<unsigned*>(&hh);
            }
            uint4* dst = reinterpret_cast<uint4*>(distq + (size_t)t * NDB_PAD + rbase);
            uint4 o0, o1, o2, o3;
            o0.x=pk[0];  o0.y=pk[1];  o0.z=pk[2];  o0.w=pk[3];
            o1.x=pk[4];  o1.y=pk[5];  o1.z=pk[6];  o1.w=pk[7];
            o2.x=pk[8];  o2.y=pk[9];  o2.z=pk[10]; o2.w=pk[11];
            o3.x=pk[12]; o3.y=pk[13]; o3.z=pk[14]; o3.w=pk[15];
            dst[0]=o0; dst[1]=o1; dst[2]=o2; dst[3]=o3;
        }
        __builtin_amdgcn_s_barrier();            // dist_lds free

        if (ph + 1 < NPH) {
            ushort8 o0, o1;
            o0[0]=f32_to_bf16_rne(p0.x); o0[1]=f32_to_bf16_rne(p0.y); o0[2]=f32_to_bf16_rne(p0.z); o0[3]=f32_to_bf16_rne(p0.w);
            o0[4]=f32_to_bf16_rne(p1.x); o0[5]=f32_to_bf16_rne(p1.y); o0[6]=f32_to_bf16_rne(p1.z); o0[7]=f32_to_bf16_rne(p1.w);
            o1[0]=f32_to_bf16_rne(p2.x); o1[1]=f32_to_bf16_rne(p2.y); o1[2]=f32_to_bf16_rne(p2.z); o1[3]=f32_to_bf16_rne(p2.w);
            o1[4]=f32_to_bf16_rne(p3.x); o1[5]=f32_to_bf16_rne(p3.y); o1[6]=f32_to_bf16_rne(p3.z); o1[7]=f32_to_bf16_rne(p3.w);
            *reinterpret_cast<ushort8*>(&xb[nxt][sr * XB_STR + sc * 16]) = o0;
            *reinterpret_cast<ushort8*>(&xb[nxt][sr * XB_STR + sc * 16 + 8]) = o1;
            float s = p0.x*p0.x + p0.y*p0.y + p0.z*p0.z + p0.w*p0.w
                    + p1.x*p1.x + p1.y*p1.y + p1.z*p1.z + p1.w*p1.w
                    + p2.x*p2.x + p2.y*p2.y + p2.z*p2.z + p2.w*p2.w
                    + p3.x*p3.x + p3.y*p3.y + p3.z*p3.z + p3.w*p3.w;
            s += __shfl_xor(s, 1, 8); s += __shfl_xor(s, 2, 8); s += __shfl_xor(s, 4, 8);
            if (sc == 0) xsq_lds[nxt][sr] = s;
        }
    }

    // fp16-rounded block min (monotone rounding: min(round(x)) == round(min(x)))
    blkmin[(size_t)t * NBLK + blockIdx.x] = __half2float(__float2half(mnall));
}

// ---------------- Kernel C: exact-threshold filter + rank select + l2 + KL ----------------
__global__ __launch_bounds__(512)
void k_sel(const __half* __restrict__ distq, const float* __restrict__ blkmin,
           const float* __restrict__ Tq, const float* __restrict__ X,
           const int* __restrict__ q_indices,
           const int* __restrict__ pre_indices,
           const float* __restrict__ pre_weights,
           float* __restrict__ kl_out) {
    const int q = blockIdx.x, t = threadIdx.x, w = t >> 6, lane = t & 63;
    __shared__ float tau_s;
    __shared__ int cnt_s;
    __shared__ float cv[CAP]; __shared__ int cidx[CAP];
    __shared__ int post_idx[KNN];
    __shared__ float l2s[KNN];
    __shared__ float post_w[KNN];
    __shared__ int u_idx[2 * KNN]; __shared__ float u_p[2 * KNN]; __shared__ float u_q[2 * KNN];

    if (t == 0) cnt_s = 0;
    if (w == 0) {
        // exact 16th smallest of the 391 block minima (valid upper bound on true 16th)
        float m[7];
#pragma unroll
        for (int k = 0; k < 7; ++k) {
            int i = lane + 64 * k;
            m[k] = (i < NBLK) ? blkmin[(size_t)q * NBLK + i] : FBIG;
        }
        float tau = FBIG;
        for (int e = 0; e < KNN; ++e) {
            float best = m[0];
#pragma unroll
            for (int k = 1; k < 7; ++k) best = fminf(best, m[k]);
            float b = best;
#pragma unroll
            for (int s = 1; s < 64; s <<= 1) b = fminf(b, __shfl_xor(b, s, 64));
            tau = b;
            unsigned long long has = __ballot(best == b);
            int src = (int)__builtin_ctzll(has);
            if (lane == src) {       // remove exactly one instance
                bool done = false;
#pragma unroll
                for (int k = 0; k < 7; ++k) {
                    bool hit = !done && (m[k] == b);
                    if (hit) { m[k] = FBIG; done = true; }
                }
            }
        }
        if (lane == 0) tau_s = tau;
    }
    __syncthreads();
    const float tau = tau_s;

    // streaming filtered append (hits are ~16-30 per query total)
    const __half* dq = distq + (size_t)q * NDB_PAD;
    const uint4* src = reinterpret_cast<const uint4*>(dq) + w * WQ4;
    const int jbase = w * WSLICE;

#define LOADI(dst, i)                                                     \
    {   int idx_ = (i) * 64 + lane;                                       \
        dst = src[idx_ < WQ4 ? idx_ : WQ4 - 1];                           \
        if (idx_ >= WQ4) { dst.x = dst.y = dst.z = dst.w = HINF4; } }

    uint4 c0, c1;
    LOADI(c0, 0); LOADI(c1, 1);
    for (int i = 0; i < NIT; ++i) {
        uint4 c2;
        if (i + 2 < NIT) { LOADI(c2, i + 2); }
        else { c2.x = c2.y = c2.z = c2.w = HINF4; }
        float fl0, fl1, fl2, fl3, fl4, fl5, fl6, fl7;
        {
            __half2 hh;
            hh = u2h(c0.x); fl0 = __half2float(__low2half(hh)); fl1 = __half2float(__high2half(hh));
            hh = u2h(c0.y); fl2 = __half2float(__low2half(hh)); fl3 = __half2float(__high2half(hh));
            hh = u2h(c0.z); fl4 = __half2float(__low2half(hh)); fl5 = __half2float(__high2half(hh));
            hh = u2h(c0.w); fl6 = __half2float(__low2half(hh)); fl7 = __half2float(__high2half(hh));
        }
        float fmn = fminf(fminf(fminf(fl0, fl1), fminf(fl2, fl3)),
                          fminf(fminf(fl4, fl5), fminf(fl6, fl7)));
        if (fmn <= tau) {            // rare divergent append path
            int j8 = jbase + (i * 64 + lane) * 8;
#define APP(v, e)                                                          \
            if ((v) <= tau) {                                              \
                int pos = atomicAdd(&cnt_s, 1);                            \
                if (pos < CAP) { cv[pos] = (v); cidx[pos] = j8 + (e); }    \
            }
            APP(fl0, 0) APP(fl1, 1) APP(fl2, 2) APP(fl3, 3)
            APP(fl4, 4) APP(fl5, 5) APP(fl6, 6) APP(fl7, 7)
#undef APP
        }
        c0 = c1; c1 = c2;
    }
#undef LOADI
    __syncthreads();

    const int n = (cnt_s < CAP) ? cnt_s : CAP;
    // rank-based exact select of 16 smallest (deterministic: (val, idx) total order)
    for (int e = t; e < n; e += 512) {
        float v = cv[e]; int id = cidx[e];
        int r = 0;
        for (int i2 = 0; i2 < n; ++i2) {
            float vi = cv[i2];
            r += (vi < v) || (vi == v && cidx[i2] < id);
        }
        if (r < KNN) post_idx[r] = id;
    }
    __syncthreads();

    if (t < 256) {   // exact f32 l2 for the selected 16 (16 threads x 8 dims each)
        int nn = t >> 4, l = t & 15;
        int idx = post_idx[nn];
        const float* tr = Tq + q * DIM + l * 8;
        const float* xr = X + (size_t)idx * DIM + l * 8;
        float s = 0.f;
#pragma unroll
        for (int kk = 0; kk < 8; ++kk) { float df = tr[kk] - xr[kk]; s = fmaf(df, df, s); }
#pragma unroll
        for (int m = 1; m < 16; m <<= 1) s += __shfl_xor(s, m, 64);
        if (l == 0) l2s[nn] = s;
    }
    __syncthreads();

    if (t == 0) {
        float mx = -FBIG;
        for (int i = 0; i < KNN; ++i) { float v = -l2s[i] * TAU_INV; post_w[i] = v; if (v > mx) mx = v; }
        float sum = 0.f;
        for (int i = 0; i < KNN; ++i) { float e = expf(post_w[i] - mx); post_w[i] = e; sum += e; }
        float inv = 1.f / sum;
        for (int i = 0; i < KNN; ++i) post_w[i] *= inv;

        int qi = q_indices[q];
        int cnt2 = KNN;
        for (int i = 0; i < KNN; ++i) { u_idx[i] = post_idx[i]; u_q[i] = post_w[i]; u_p[i] = 0.f; }
        for (int m = 0; m < KNN; ++m) {
            int pi = pre_indices[qi * KNN + m];
            float pwm = pre_weights[qi * KNN + m];
            int f = -1;
            for (int s2 = 0; s2 < cnt2; ++s2) if (u_idx[s2] == pi) { f = s2; break; }
            if (f >= 0) u_p[f] = pwm;
            else { u_idx[cnt2] = pi; u_p[cnt2] = pwm; u_q[cnt2] = 0.f; ++cnt2; }
        }
        float Zp = 0.f, Zq = 0.f;
        for (int s2 = 0; s2 < cnt2; ++s2) { Zp += fmaxf(u_p[s2], EPSC); Zq += fmaxf(u_q[s2], EPSC); }
        float kl = 0.f;
        float izp = 1.f / Zp, izq = 1.f / Zq;
        for (int s2 = 0; s2 < cnt2; ++s2) {
            float pp = fmaxf(u_p[s2], EPSC) * izp;
            float qv = fmaxf(u_q[s2], EPSC) * izq;
            kl += pp * (logf(pp) - logf(qv));
        }
        kl_out[q] = kl;
    }
}

// ---------------- Kernel D: final reduction + outputs ----------------
__global__ void k_out(const float* __restrict__ kl, const float* __restrict__ W,
                      float* __restrict__ out) {
    int t = threadIdx.x;
    float s_kl = (t < BQ) ? kl[t] : 0.f;
    float s_w = 0.f;
    for (int i = t; i < DIM * DIM; i += 256) { float w = W[i]; s_w = fmaf(w, w, s_w); }
#pragma unroll
    for (int m = 32; m >= 1; m >>= 1) {
        s_kl += __shfl_xor(s_kl, m, 64);
        s_w += __shfl_xor(s_w, m, 64);
    }
    __shared__ float rk[4], rw[4];
    if ((t & 63) == 0) { rk[t >> 6] = s_kl; rw[t >> 6] = s_w; }
    __syncthreads();
    if (t == 0) {
        float kls = rk[0] + rk[1] + rk[2] + rk[3];
        float wss = rw[0] + rw[1] + rw[2] + rw[3];
        float knn = kls * (1.0f / BQ);
        float reg = 0.5f * wss;
        out[0] = 1.0f * knn + 1e-4f * reg;
        out[1] = 0.f;
        out[2] = knn;
    }
}

extern "C" void kernel_launch(void* const* d_in, const int* in_sizes, int n_in,
                              void* d_out, int out_size, void* d_ws, size_t ws_size,
                              hipStream_t stream) {
    const float* q_batch     = (const float*)d_in[0];
    const int*   q_indices   = (const int*)d_in[1];
    const float* X           = (const float*)d_in[2];
    const float* W           = (const float*)d_in[3];
    const int*   pre_indices = (const int*)d_in[4];
    const float* pre_weights = (const float*)d_in[5];

    char* ws = (char*)d_ws;
    float*  Tq     = (float*)(ws);                 // 128KB
    ushort* Tqb    = (ushort*)(ws + 131072);       // 64KB
    float*  klv    = (float*)(ws + 196608);        // 1KB
    float*  blkmin = (float*)(ws + 262144);        // 256*391*4B = 400KB
    __half* distq  = (__half*)(ws + 786432);       // 256 * 100096 fp16 = 51.25MB

    k_tq<<<dim3(BQ), dim3(DIM), 0, stream>>>(q_batch, W, Tq, Tqb);
    k_dist<<<dim3(NBLK), dim3(256), 0, stream>>>(Tqb, X, distq, blkmin);
    k_sel<<<dim3(BQ), dim3(512), 0, stream>>>(distq, blkmin, Tq, X,
                                              q_indices, pre_indices, pre_weights, klv);
    k_out<<<dim3(1), dim3(256), 0, stream>>>(klv, W, (float*)d_out);
}